// Round 1
// baseline (1807.733 us; speedup 1.0000x reference)
//
#include <hip/hip_runtime.h>

// ---------------------------------------------------------------------------
// ConditionalRealNVP on MI355X: 8 coupling layers, f16 MFMA GEMMs + fused
// permute/affine epilogues.  All activations f16 (fp32 accumulate), z/logdet
// kept fp32.
// ---------------------------------------------------------------------------

#define L_LAYERS 8
#define DDIM     256
#define HDIM     1024
#define BROWS    8192
#define ADIM     128          // D/2
#define BDIM_    128          // D - A
#define INDIM    3200         // A + 3*H
#define CTEDIM   3072         // 3*H
#define CLIPV    3.0f

typedef _Float16 f16x8 __attribute__((ext_vector_type(8)));
typedef _Float16 f16x4 __attribute__((ext_vector_type(4)));
typedef float    f32x4 __attribute__((ext_vector_type(4)));

__device__ __forceinline__ void async_copy16(const _Float16* g, _Float16* s) {
    __builtin_amdgcn_global_load_lds((const __attribute__((address_space(1))) void*)g,
                                     (__attribute__((address_space(3))) void*)s,
                                     16, 0, 0);
}

// ---------------------------------------------------------------------------
// MFMA GEMM: C[m][n] = act( sum_k A[m][k] * Bt[n][k] + bias[n] )
// A comes from up to two row-major f16 sources: k < K0 -> A0 (lda0),
// k >= K0 -> A1 (lda1).  128x128 tile, BK=64, 4 waves, m97 structure.
// MODE 0: silu -> f16 Hout (ldh == N).  MODE 1: bias only -> fp32 Fout.
// ---------------------------------------------------------------------------
template <int MODE>
__global__ __launch_bounds__(256)
void gemm_mfma(const _Float16* __restrict__ A0, int lda0, int K0,
               const _Float16* __restrict__ A1, int lda1,
               const _Float16* __restrict__ Bt, int ldb,
               const float* __restrict__ bias,
               _Float16* __restrict__ Hout,
               float* __restrict__ Fout,
               int N, int K)
{
    __shared__ __attribute__((aligned(16))) _Float16 As[128 * 64];
    __shared__ __attribute__((aligned(16))) _Float16 Bs[128 * 64];

    const int tid  = threadIdx.x;
    const int wave = tid >> 6;
    const int lane = tid & 63;
    const int m0 = blockIdx.y * 128;
    const int n0 = blockIdx.x * 128;
    const int wm = (wave >> 1) * 64;   // wave row offset in tile
    const int wn = (wave & 1) * 64;    // wave col offset in tile

    f32x4 acc[4][4];
#pragma unroll
    for (int i = 0; i < 4; ++i)
#pragma unroll
        for (int j = 0; j < 4; ++j)
            acc[i][j] = (f32x4){0.f, 0.f, 0.f, 0.f};

    const int rsub = lane >> 3;        // 0..7  (row within wave's 8-row chunk)
    const int csub = (lane & 7) * 8;   // 0..56 (col, 8 halfs = 16B)

    for (int k0 = 0; k0 < K; k0 += 64) {
        // ---- stage A tile (128 x 64) ----
        const _Float16* abase;
        int alda, akoff;
        if (k0 < K0) { abase = A0; alda = lda0; akoff = k0; }
        else         { abase = A1; alda = lda1; akoff = k0 - K0; }
#pragma unroll
        for (int i = 0; i < 4; ++i) {
            const int row = i * 32 + wave * 8 + rsub;
            const _Float16* src = abase + (size_t)(m0 + row) * alda + akoff + csub;
            async_copy16(src, &As[(i * 32 + wave * 8) * 64]);
        }
        // ---- stage B tile (128 x 64) from Bt (N x K) ----
#pragma unroll
        for (int i = 0; i < 4; ++i) {
            const int row = i * 32 + wave * 8 + rsub;
            const _Float16* src = Bt + (size_t)(n0 + row) * ldb + k0 + csub;
            async_copy16(src, &Bs[(i * 32 + wave * 8) * 64]);
        }
        __syncthreads();   // drains vmcnt before use

        // ---- MFMA on the tile: 2 k-steps of 32 ----
#pragma unroll
        for (int kk = 0; kk < 2; ++kk) {
            const int c = kk * 32 + (lane >> 4) * 8;
            f16x8 af[4], bf[4];
#pragma unroll
            for (int i = 0; i < 4; ++i) {
                af[i] = *(const f16x8*)&As[(wm + i * 16 + (lane & 15)) * 64 + c];
                bf[i] = *(const f16x8*)&Bs[(wn + i * 16 + (lane & 15)) * 64 + c];
            }
#pragma unroll
            for (int i = 0; i < 4; ++i)
#pragma unroll
                for (int j = 0; j < 4; ++j)
                    acc[i][j] = __builtin_amdgcn_mfma_f32_16x16x32_f16(af[i], bf[j], acc[i][j], 0, 0, 0);
        }
        __syncthreads();   // protect LDS before next stage
    }

    // ---- epilogue: C/D layout col = lane&15, row = (lane>>4)*4 + reg ----
    const int cn = lane & 15;
    const int rb = (lane >> 4) * 4;
#pragma unroll
    for (int j = 0; j < 4; ++j) {
        const int gn = n0 + wn + j * 16 + cn;
        const float bv = bias[gn];
#pragma unroll
        for (int i = 0; i < 4; ++i) {
            const int gm0 = m0 + wm + i * 16 + rb;
#pragma unroll
            for (int r = 0; r < 4; ++r) {
                float v = acc[i][j][r] + bv;
                if (MODE == 0) {
                    const float s = v / (1.f + __expf(-v));
                    Hout[(size_t)(gm0 + r) * N + gn] = (_Float16)s;
                } else {
                    Fout[(size_t)(gm0 + r) * N + gn] = v;
                }
            }
        }
    }
}

// ---------------------------------------------------------------------------
// Transpose + fp32 -> f16: in is (K x N) row-major fp32, out is (N x K) f16.
// 64x64 tiles, blockIdx.z = layer.
// ---------------------------------------------------------------------------
__global__ void transpose_to_f16(const float* __restrict__ in, _Float16* __restrict__ out,
                                 int K, int N, size_t inLayerStride, size_t outLayerStride)
{
    __shared__ float t[64][65];
    in  += (size_t)blockIdx.z * inLayerStride;
    out += (size_t)blockIdx.z * outLayerStride;
    const int kb = blockIdx.y * 64, nb = blockIdx.x * 64;
    const int tx = threadIdx.x & 63, ty = threadIdx.x >> 6;
#pragma unroll
    for (int i = 0; i < 64; i += 4)
        t[ty + i][tx] = in[(size_t)(kb + ty + i) * N + nb + tx];
    __syncthreads();
#pragma unroll
    for (int i = 0; i < 64; i += 4)
        out[(size_t)(nb + ty + i) * K + kb + tx] = (_Float16)t[tx][ty + i];
}

// concat(ctx, t_emb, cond_emb) -> f16, B x 3072
__global__ void build_cte(const float* __restrict__ ctx, const float* __restrict__ te,
                          const float* __restrict__ ce, _Float16* __restrict__ out)
{
    const int idx = blockIdx.x * blockDim.x + threadIdx.x;   // over B*768
    const int r = idx / (CTEDIM / 4);
    const int c = (idx % (CTEDIM / 4)) * 4;
    const float* src = (c < 1024) ? ctx + (size_t)r * 1024 + c
                     : (c < 2048) ? te  + (size_t)r * 1024 + (c - 1024)
                                  : ce  + (size_t)r * 1024 + (c - 2048);
    const float4 v = *reinterpret_cast<const float4*>(src);
    f16x4 o; o.x = (_Float16)v.x; o.y = (_Float16)v.y; o.z = (_Float16)v.z; o.w = (_Float16)v.w;
    *reinterpret_cast<f16x4*>(&out[idx * 4]) = o;
}

__global__ void build_biasSS(const float* __restrict__ bs, const float* __restrict__ bt,
                             float* __restrict__ out)
{
    const int id = blockIdx.x * 256 + threadIdx.x;   // L*256
    const int l = id >> 8, j = id & 255;
    out[id] = (j < 128) ? bs[l * 128 + j] : bt[l * 128 + (j - 128)];
}

// layer-0 x_a gather: xa[r][j] = x[r][ perm0[idx_a0[j]] ]
__global__ void gather_xa0(const float* __restrict__ x, const int* __restrict__ perm,
                           const int* __restrict__ ia, _Float16* __restrict__ xa)
{
    const int r = blockIdx.x, j = threadIdx.x;   // 128 threads
    xa[(size_t)r * ADIM + j] = (_Float16)x[(size_t)r * DDIM + perm[ia[j]]];
}

// ---------------------------------------------------------------------------
// Coupling epilogue for one layer.  Block = 128 threads = 1 row.
//   x_a[j] = zin[r][perm[ia[j]]],  x_b[j] = zin[r][perm[ib[j]]]
//   scale = clip(ss[r][j]),  shift = ss[r][128+j]
//   z_new[r][ia[j]] = x_a[j];  z_new[r][ib[j]] = x_b*exp(scale)+shift
//   logdet accumulate; next layer's x_a gather fused (from z_new in LDS).
// ---------------------------------------------------------------------------
__global__ void coupling_ep(const float* __restrict__ zin,
                            const float* __restrict__ ss,
                            const int* __restrict__ perm,
                            const int* __restrict__ ia_,
                            const int* __restrict__ ib_,
                            const int* __restrict__ permN,
                            const int* __restrict__ iaN,
                            float* __restrict__ zout,
                            _Float16* __restrict__ xaN,
                            const float* __restrict__ ldin,
                            float* __restrict__ ldout,
                            int first)
{
    const int r = blockIdx.x, j = threadIdx.x;   // j in [0,128)
    __shared__ float zrow[DDIM];
    __shared__ float part[2];

    const int ia = ia_[j], ib = ib_[j];
    const float xav = zin[(size_t)r * DDIM + perm[ia]];
    const float xbv = zin[(size_t)r * DDIM + perm[ib]];
    float sc = ss[(size_t)r * DDIM + j];
    sc = fminf(CLIPV, fmaxf(-CLIPV, sc));
    const float sh = ss[(size_t)r * DDIM + 128 + j];
    const float yb = xbv * __expf(sc) + sh;

    zrow[ia] = xav;
    zrow[ib] = yb;

    float v = sc;
#pragma unroll
    for (int off = 32; off; off >>= 1) v += __shfl_down(v, off, 64);
    if ((j & 63) == 0) part[j >> 6] = v;
    __syncthreads();

    zout[(size_t)r * DDIM + j]       = zrow[j];
    zout[(size_t)r * DDIM + 128 + j] = zrow[128 + j];
    if (xaN) xaN[(size_t)r * ADIM + j] = (_Float16)zrow[permN[iaN[j]]];
    if (j == 0) ldout[r] = (first ? 0.f : ldin[r]) + part[0] + part[1];
}

// ---------------------------------------------------------------------------
extern "C" void kernel_launch(void* const* d_in, const int* in_sizes, int n_in,
                              void* d_out, int out_size, void* d_ws, size_t ws_size,
                              hipStream_t stream)
{
    const float* x    = (const float*)d_in[0];
    const float* ctx  = (const float*)d_in[1];
    const float* temb = (const float*)d_in[2];
    const float* cemb = (const float*)d_in[3];
    const float* W1   = (const float*)d_in[4];
    const float* b1   = (const float*)d_in[5];
    const float* W2   = (const float*)d_in[6];
    const float* b2   = (const float*)d_in[7];
    const float* W3   = (const float*)d_in[8];
    const float* b3   = (const float*)d_in[9];
    const float* Ws   = (const float*)d_in[10];
    const float* bs   = (const float*)d_in[11];
    const float* Wt   = (const float*)d_in[12];
    const float* bt   = (const float*)d_in[13];
    const int*   perm = (const int*)d_in[14];
    const int*   idxa = (const int*)d_in[15];
    const int*   idxb = (const int*)d_in[16];

    float* out_z  = (float*)d_out;
    float* out_ld = out_z + (size_t)BROWS * DDIM;

    // ---- workspace layout (f16 region then fp32 region) ----
    _Float16* W1t   = (_Float16*)d_ws;                      // L*H*IN
    _Float16* W2t   = W1t   + (size_t)L_LAYERS * HDIM * INDIM;
    _Float16* W3t   = W2t   + (size_t)L_LAYERS * HDIM * HDIM;
    _Float16* WsWtT = W3t   + (size_t)L_LAYERS * HDIM * HDIM;   // L*256*H
    _Float16* cte   = WsWtT + (size_t)L_LAYERS * 256 * HDIM;    // B*3072
    _Float16* xa    = cte   + (size_t)BROWS * CTEDIM;           // B*128
    _Float16* hA    = xa    + (size_t)BROWS * ADIM;             // B*H
    _Float16* hB    = hA    + (size_t)BROWS * HDIM;             // B*H
    float* biasSS = (float*)(hB + (size_t)BROWS * HDIM);        // L*256
    float* ssbuf  = biasSS + (size_t)L_LAYERS * 256;            // B*256
    float* z0     = ssbuf  + (size_t)BROWS * DDIM;              // B*256
    float* z1     = z0     + (size_t)BROWS * DDIM;              // B*256
    float* ldacc  = z1     + (size_t)BROWS * DDIM;              // B

    // ---- setup: weight transposes (fp32 -> f16, K x N -> N x K) ----
    transpose_to_f16<<<dim3(HDIM / 64, INDIM / 64, L_LAYERS), 256, 0, stream>>>(
        W1, W1t, INDIM, HDIM, (size_t)INDIM * HDIM, (size_t)HDIM * INDIM);
    transpose_to_f16<<<dim3(HDIM / 64, HDIM / 64, L_LAYERS), 256, 0, stream>>>(
        W2, W2t, HDIM, HDIM, (size_t)HDIM * HDIM, (size_t)HDIM * HDIM);
    transpose_to_f16<<<dim3(HDIM / 64, HDIM / 64, L_LAYERS), 256, 0, stream>>>(
        W3, W3t, HDIM, HDIM, (size_t)HDIM * HDIM, (size_t)HDIM * HDIM);
    // Ws -> rows [0,128), Wt -> rows [128,256) of the fused 256 x H B-matrix
    transpose_to_f16<<<dim3(BDIM_ / 64, HDIM / 64, L_LAYERS), 256, 0, stream>>>(
        Ws, WsWtT, HDIM, BDIM_, (size_t)HDIM * BDIM_, (size_t)256 * HDIM);
    transpose_to_f16<<<dim3(BDIM_ / 64, HDIM / 64, L_LAYERS), 256, 0, stream>>>(
        Wt, WsWtT + (size_t)BDIM_ * HDIM, HDIM, BDIM_, (size_t)HDIM * BDIM_, (size_t)256 * HDIM);

    build_cte<<<(BROWS * (CTEDIM / 4)) / 256, 256, 0, stream>>>(ctx, temb, cemb, cte);
    build_biasSS<<<L_LAYERS, 256, 0, stream>>>(bs, bt, biasSS);
    gather_xa0<<<BROWS, 128, 0, stream>>>(x, perm, idxa, xa);

    // ---- 8 coupling layers ----
    const float* zin = x;
    for (int l = 0; l < L_LAYERS; ++l) {
        const _Float16* w1 = W1t + (size_t)l * HDIM * INDIM;
        const _Float16* w2 = W2t + (size_t)l * HDIM * HDIM;
        const _Float16* w3 = W3t + (size_t)l * HDIM * HDIM;
        const _Float16* w4 = WsWtT + (size_t)l * 256 * HDIM;

        // GEMM1: [xa | cte] (K=3200) @ W1 -> silu -> hA
        gemm_mfma<0><<<dim3(HDIM / 128, BROWS / 128), 256, 0, stream>>>(
            xa, ADIM, ADIM, cte, CTEDIM, w1, INDIM, b1 + (size_t)l * HDIM,
            hA, nullptr, HDIM, INDIM);
        // GEMM2: hA @ W2 -> silu -> hB
        gemm_mfma<0><<<dim3(HDIM / 128, BROWS / 128), 256, 0, stream>>>(
            hA, HDIM, INDIM, nullptr, 0, w2, HDIM, b2 + (size_t)l * HDIM,
            hB, nullptr, HDIM, HDIM);
        // GEMM3: hB @ W3 -> silu -> hA
        gemm_mfma<0><<<dim3(HDIM / 128, BROWS / 128), 256, 0, stream>>>(
            hB, HDIM, INDIM, nullptr, 0, w3, HDIM, b3 + (size_t)l * HDIM,
            hA, nullptr, HDIM, HDIM);
        // GEMM4: hA @ [Ws|Wt] -> fp32 ss (scale||shift)
        gemm_mfma<1><<<dim3(256 / 128, BROWS / 128), 256, 0, stream>>>(
            hA, HDIM, INDIM, nullptr, 0, w4, HDIM, biasSS + (size_t)l * 256,
            nullptr, ssbuf, 256, HDIM);

        // epilogue
        float* zout = (l == L_LAYERS - 1) ? out_z : ((l & 1) ? z1 : z0);
        const int last = (l == L_LAYERS - 1);
        coupling_ep<<<BROWS, 128, 0, stream>>>(
            zin, ssbuf,
            perm + (size_t)l * DDIM, idxa + (size_t)l * ADIM, idxb + (size_t)l * ADIM,
            last ? nullptr : perm + (size_t)(l + 1) * DDIM,
            last ? nullptr : idxa + (size_t)(l + 1) * ADIM,
            zout, last ? nullptr : xa,
            ldacc, last ? out_ld : ldacc, l == 0);
        zin = zout;
    }
}

// Round 3
// 1520.788 us; speedup vs baseline: 1.1887x; 1.1887x over previous
//
#include <hip/hip_runtime.h>

// ---------------------------------------------------------------------------
// ConditionalRealNVP on MI355X.
// Layer-invariant ctx-part of GEMM1 hoisted into ONE 8192x8192x3072 GEMM.
// Big GEMM + GEMM2/3: 256x256 8-phase counted-vmcnt MFMA template (T3+T4+T5)
// with pre-swizzled-source LDS (T2, rule #21).  RACE FIX vs round 2: the
// counted vmcnt is issued BEFORE the last barrier of each K-iteration so all
// waves' global_load_lds writes are visible before any wave reads the tile.
// ---------------------------------------------------------------------------

#define L_LAYERS 8
#define DDIM     256
#define HDIM     1024
#define BROWS    8192
#define ADIM     128          // D/2
#define BDIM_    128          // D - A
#define INDIM    3200         // A + 3*H
#define CTEDIM   3072         // 3*H
#define CLIPV    3.0f

typedef _Float16 f16x8 __attribute__((ext_vector_type(8)));
typedef _Float16 f16x4 __attribute__((ext_vector_type(4)));
typedef float    f32x4 __attribute__((ext_vector_type(4)));

__device__ __forceinline__ void async_copy16(const _Float16* g, _Float16* s) {
    __builtin_amdgcn_global_load_lds((const __attribute__((address_space(1))) void*)g,
                                     (__attribute__((address_space(3))) void*)s,
                                     16, 0, 0);
}

// ---------------------------------------------------------------------------
// 256x256 8-phase template GEMM: C = act(A @ Bt^T + bias)
// A row-major MxK f16, Bt row-major NxK f16.  512 threads / 8 waves (2Mx4N),
// BK=64 as two k-halves of 32; per operand a 4-half-slot LDS ring
// ([256][32] f16 = 16KB/slot).  LDS is written linearly by global_load_lds;
// the quarter swizzle (qP = qL ^ ((row>>1)&3)) is applied by permuting the
// GLOBAL source address, and undone on the read side by a per-lane-constant
// XOR -> conflict-free ds_read_b128 (8 distinct bank quads per 8-lane group).
// vmcnt(4) once per K-tile BEFORE the tile's final barrier (m201 placement).
// MODE 0: raw f16 store.  MODE 1: bias + silu -> f16.
// ---------------------------------------------------------------------------
template <int MODE>
__global__ __launch_bounds__(512, 2)
void gemm8p(const _Float16* __restrict__ A, int lda,
            const _Float16* __restrict__ Bt, int ldb,
            const float* __restrict__ bias,
            _Float16* __restrict__ C, int ldc,
            int K, int gx)
{
    __shared__ __attribute__((aligned(16))) _Float16 lds[65536];   // 128 KiB

    const int tid  = threadIdx.x;
    const int w    = tid >> 6, lane = tid & 63;
    const int wm   = w >> 2,   wn   = w & 3;

    const int nwg = gridDim.x;
    const int bid = blockIdx.x;
    const int wg  = ((nwg & 7) == 0) ? ((bid & 7) * (nwg >> 3) + (bid >> 3)) : bid;
    const int bx  = wg % gx, by = wg / gx;
    const int m0  = by << 8, n0 = bx << 8;

    const int NT = K >> 6;   // NT >= 2 assumed (K >= 128)

    // staging: thread covers rows (tid>>2) and +128; source quarter is
    // pre-swizzled so the LINEAR LDS write realizes the XOR-swizzled layout.
    const int srow = tid >> 2;
    const int srcq = ((tid & 3) ^ ((tid >> 3) & 3)) * 8;     // f16 offset
    const _Float16* gA = A  + (size_t)(m0 + srow) * lda + srcq;
    const _Float16* gB = Bt + (size_t)(n0 + srow) * ldb + srcq;
    const size_t a128 = (size_t)128 * lda;
    const size_t b128 = (size_t)128 * ldb;
    _Float16* ldsA = lds + w * 512;            // wave-uniform LDS stage bases
    _Float16* ldsB = lds + 32768 + w * 512;

#define STG_A(t_, kh_) do { if ((t_) < NT) { \
        const _Float16* s_ = gA + (size_t)(t_) * 64 + (kh_) * 32; \
        _Float16* d_ = ldsA + (((2 * (t_) + (kh_)) & 3) << 13); \
        async_copy16(s_, d_); async_copy16(s_ + a128, d_ + 4096); } } while (0)
#define STG_B(t_, kh_) do { if ((t_) < NT) { \
        const _Float16* s_ = gB + (size_t)(t_) * 64 + (kh_) * 32; \
        _Float16* d_ = ldsB + (((2 * (t_) + (kh_)) & 3) << 13); \
        async_copy16(s_, d_); async_copy16(s_ + b128, d_ + 4096); } } while (0)

    f32x4 acc[8][4];
#pragma unroll
    for (int i = 0; i < 8; ++i)
#pragma unroll
        for (int j = 0; j < 4; ++j) acc[i][j] = (f32x4){0.f, 0.f, 0.f, 0.f};

    // prologue: tile0 complete (8 loads) + tile1 kh0 (4 loads)
    STG_A(0, 0); STG_B(0, 0); STG_A(0, 1); STG_B(0, 1);
    STG_A(1, 0); STG_B(1, 0);
    // tile0 resident for ALL waves: own-wave drain, then barrier.
    asm volatile("s_waitcnt vmcnt(4)" ::: "memory");
    __builtin_amdgcn_s_barrier();

    // read-side swizzle: per-lane constant quarter XOR
    const int qsw = ((lane & 15) >> 1) & 3;
    const int q16 = (((lane >> 4) ^ qsw)) << 4;              // byte offset
    const int rA0 = wm * 128 + (lane & 15);
    const int rA1 = rA0 + 64;
    const int rB  = wn * 64 + (lane & 15);
    const char* ldsc = (const char*)&lds[0];

    f16x8 bf[4];

#define LOADB(sl) { _Pragma("unroll") for (int f = 0; f < 4; ++f) \
        bf[f] = *(const f16x8*)(ldsc + 65536 + (sl) + (rB + f * 16) * 64 + q16); }
#define LOADA(sl, rb_) { _Pragma("unroll") for (int f = 0; f < 4; ++f) \
        af[f] = *(const f16x8*)(ldsc + (sl) + ((rb_) + f * 16) * 64 + q16); }
#define MFMA16(mo) { __builtin_amdgcn_s_setprio(1); \
        _Pragma("unroll") for (int f = 0; f < 4; ++f) \
        _Pragma("unroll") for (int nf = 0; nf < 4; ++nf) \
            acc[(mo) + f][nf] = __builtin_amdgcn_mfma_f32_16x16x32_f16(af[f], bf[nf], acc[(mo) + f][nf], 0, 0, 0); \
        __builtin_amdgcn_s_setprio(0); }
#define BAR() __builtin_amdgcn_s_barrier()
#define LGKM0() do { asm volatile("s_waitcnt lgkmcnt(0)" ::: "memory"); \
        __builtin_amdgcn_sched_barrier(0); } while (0)

    for (int T = 0; T < NT; ++T) {
        const int s0 = ((2 * T) & 3) << 14;        // byte offset of kh0 slot
        const int s1 = ((2 * T + 1) & 3) << 14;

        { f16x8 af[4]; LOADB(s0); LOADA(s0, rA0); STG_A(T + 1, 1);
          BAR(); LGKM0(); MFMA16(0); BAR(); }
        { f16x8 af[4]; LOADA(s0, rA1); STG_B(T + 1, 1);
          BAR(); LGKM0(); MFMA16(4); BAR(); }
        { f16x8 af[4]; LOADB(s1); LOADA(s1, rA0); STG_A(T + 2, 0);
          BAR(); LGKM0(); MFMA16(0); BAR(); }
        { f16x8 af[4]; LOADA(s1, rA1); STG_B(T + 2, 0);
          BAR(); LGKM0(); MFMA16(4);
          // RACE FIX: tile T+1 residency gate BEFORE the barrier, so every
          // wave has drained its staging writes before any wave reads them.
          if (T + 2 < NT) { asm volatile("s_waitcnt vmcnt(4)" ::: "memory"); }
          else            { asm volatile("s_waitcnt vmcnt(0)" ::: "memory"); }
          BAR(); }
    }

    // epilogue: C/D layout col = lane&15, row = (lane>>4)*4 + reg
    const int cn = lane & 15, rb4 = (lane >> 4) * 4;
#pragma unroll
    for (int i = 0; i < 8; ++i) {
        const int gm = m0 + wm * 128 + i * 16 + rb4;
#pragma unroll
        for (int j = 0; j < 4; ++j) {
            const int gn = n0 + wn * 64 + j * 16 + cn;
            const float bv = (MODE == 1) ? bias[gn] : 0.f;
#pragma unroll
            for (int r = 0; r < 4; ++r) {
                float v = acc[i][j][r] + bv;
                if (MODE == 1) v = v / (1.f + __expf(-v));
                C[(size_t)(gm + r) * ldc + gn] = (_Float16)v;
            }
        }
    }
#undef STG_A
#undef STG_B
#undef LOADB
#undef LOADA
#undef MFMA16
#undef BAR
#undef LGKM0
}

// ---------------------------------------------------------------------------
// 128x128 m97-style GEMM for small shapes (GEMM1' K=128 w/ pre-add, GEMM4).
// Same pre-swizzled-source LDS trick ([128][64] f16, qP = qL ^ (row&7)).
// MODE 0: silu(acc+bias+pre)->f16.  MODE 1: acc+bias->fp32.
// ---------------------------------------------------------------------------
template <int MODE>
__global__ __launch_bounds__(256)
void gemm_mfma(const _Float16* __restrict__ A0, int lda0,
               const _Float16* __restrict__ Bt, int ldb,
               const float* __restrict__ bias,
               const _Float16* __restrict__ preadd, int ldpre,
               _Float16* __restrict__ Hout,
               float* __restrict__ Fout,
               int N, int K)
{
    __shared__ __attribute__((aligned(16))) _Float16 As[128 * 64];
    __shared__ __attribute__((aligned(16))) _Float16 Bs[128 * 64];

    const int tid  = threadIdx.x;
    const int wave = tid >> 6;
    const int lane = tid & 63;
    const int m0 = blockIdx.y * 128;
    const int n0 = blockIdx.x * 128;
    const int wm = (wave >> 1) * 64;
    const int wn = (wave & 1) * 64;

    f32x4 acc[4][4];
#pragma unroll
    for (int i = 0; i < 4; ++i)
#pragma unroll
        for (int j = 0; j < 4; ++j)
            acc[i][j] = (f32x4){0.f, 0.f, 0.f, 0.f};

    const int rsub = lane >> 3;
    const int csub = ((lane & 7) ^ (lane >> 3)) * 8;   // pre-swizzled source quarter

    for (int k0 = 0; k0 < K; k0 += 64) {
#pragma unroll
        for (int i = 0; i < 4; ++i) {
            const int row = i * 32 + wave * 8 + rsub;
            async_copy16(A0 + (size_t)(m0 + row) * lda0 + k0 + csub,
                         &As[(i * 32 + wave * 8) * 64]);
        }
#pragma unroll
        for (int i = 0; i < 4; ++i) {
            const int row = i * 32 + wave * 8 + rsub;
            async_copy16(Bt + (size_t)(n0 + row) * ldb + k0 + csub,
                         &Bs[(i * 32 + wave * 8) * 64]);
        }
        __syncthreads();   // full drain (vmcnt 0) + barrier — correct by construction

#pragma unroll
        for (int kk = 0; kk < 2; ++kk) {
            const int c = ((kk * 4 + (lane >> 4)) ^ (lane & 7)) * 8;  // swizzled read
            f16x8 af[4], bfr[4];
#pragma unroll
            for (int i = 0; i < 4; ++i) {
                af[i]  = *(const f16x8*)&As[(wm + i * 16 + (lane & 15)) * 64 + c];
                bfr[i] = *(const f16x8*)&Bs[(wn + i * 16 + (lane & 15)) * 64 + c];
            }
#pragma unroll
            for (int i = 0; i < 4; ++i)
#pragma unroll
                for (int j = 0; j < 4; ++j)
                    acc[i][j] = __builtin_amdgcn_mfma_f32_16x16x32_f16(af[i], bfr[j], acc[i][j], 0, 0, 0);
        }
        __syncthreads();
    }

    const int cn = lane & 15;
    const int rb = (lane >> 4) * 4;
#pragma unroll
    for (int j = 0; j < 4; ++j) {
        const int gn = n0 + wn + j * 16 + cn;
        const float bv = bias[gn];
#pragma unroll
        for (int i = 0; i < 4; ++i) {
            const int gm0 = m0 + wm + i * 16 + rb;
#pragma unroll
            for (int r = 0; r < 4; ++r) {
                float v = acc[i][j][r] + bv;
                if (MODE == 0) {
                    v += (float)preadd[(size_t)(gm0 + r) * ldpre + gn];
                    const float s = v / (1.f + __expf(-v));
                    Hout[(size_t)(gm0 + r) * N + gn] = (_Float16)s;
                } else {
                    Fout[(size_t)(gm0 + r) * N + gn] = v;
                }
            }
        }
    }
}

// ---------------------------------------------------------------------------
// Transpose + fp32 -> f16: in (K x N) row-major fp32 -> out (N x K) f16.
// ---------------------------------------------------------------------------
__global__ void transpose_to_f16(const float* __restrict__ in, _Float16* __restrict__ out,
                                 int K, int N, size_t inLayerStride, size_t outLayerStride)
{
    __shared__ float t[64][65];
    in  += (size_t)blockIdx.z * inLayerStride;
    out += (size_t)blockIdx.z * outLayerStride;
    const int kb = blockIdx.y * 64, nb = blockIdx.x * 64;
    const int tx = threadIdx.x & 63, ty = threadIdx.x >> 6;
#pragma unroll
    for (int i = 0; i < 64; i += 4)
        t[ty + i][tx] = in[(size_t)(kb + ty + i) * N + nb + tx];
    __syncthreads();
#pragma unroll
    for (int i = 0; i < 64; i += 4)
        out[(size_t)(nb + ty + i) * K + kb + tx] = (_Float16)t[tx][ty + i];
}

// concat(ctx, t_emb, cond_emb) -> f16, B x 3072
__global__ void build_cte(const float* __restrict__ ctx, const float* __restrict__ te,
                          const float* __restrict__ ce, _Float16* __restrict__ out)
{
    const int idx = blockIdx.x * blockDim.x + threadIdx.x;   // over B*768
    const int r = idx / (CTEDIM / 4);
    const int c = (idx % (CTEDIM / 4)) * 4;
    const float* src = (c < 1024) ? ctx + (size_t)r * 1024 + c
                     : (c < 2048) ? te  + (size_t)r * 1024 + (c - 1024)
                                  : ce  + (size_t)r * 1024 + (c - 2048);
    const float4 v = *reinterpret_cast<const float4*>(src);
    f16x4 o; o.x = (_Float16)v.x; o.y = (_Float16)v.y; o.z = (_Float16)v.z; o.w = (_Float16)v.w;
    *reinterpret_cast<f16x4*>(&out[idx * 4]) = o;
}

__global__ void build_biasSS(const float* __restrict__ bs, const float* __restrict__ bt,
                             float* __restrict__ out)
{
    const int id = blockIdx.x * 256 + threadIdx.x;   // L*256
    const int l = id >> 8, j = id & 255;
    out[id] = (j < 128) ? bs[l * 128 + j] : bt[l * 128 + (j - 128)];
}

__global__ void gather_xa0(const float* __restrict__ x, const int* __restrict__ perm,
                           const int* __restrict__ ia, _Float16* __restrict__ xa)
{
    const int r = blockIdx.x, j = threadIdx.x;   // 128 threads
    xa[(size_t)r * ADIM + j] = (_Float16)x[(size_t)r * DDIM + perm[ia[j]]];
}

// ---------------------------------------------------------------------------
// Coupling epilogue (1 row / 128-thread block); fuses next layer's x_a gather.
// ---------------------------------------------------------------------------
__global__ void coupling_ep(const float* __restrict__ zin,
                            const float* __restrict__ ss,
                            const int* __restrict__ perm,
                            const int* __restrict__ ia_,
                            const int* __restrict__ ib_,
                            const int* __restrict__ permN,
                            const int* __restrict__ iaN,
                            float* __restrict__ zout,
                            _Float16* __restrict__ xaN,
                            const float* __restrict__ ldin,
                            float* __restrict__ ldout,
                            int first)
{
    const int r = blockIdx.x, j = threadIdx.x;   // j in [0,128)
    __shared__ float zrow[DDIM];
    __shared__ float part[2];

    const int ia = ia_[j], ib = ib_[j];
    const float xav = zin[(size_t)r * DDIM + perm[ia]];
    const float xbv = zin[(size_t)r * DDIM + perm[ib]];
    float sc = ss[(size_t)r * DDIM + j];
    sc = fminf(CLIPV, fmaxf(-CLIPV, sc));
    const float sh = ss[(size_t)r * DDIM + 128 + j];
    const float yb = xbv * __expf(sc) + sh;

    zrow[ia] = xav;
    zrow[ib] = yb;

    float v = sc;
#pragma unroll
    for (int off = 32; off; off >>= 1) v += __shfl_down(v, off, 64);
    if ((j & 63) == 0) part[j >> 6] = v;
    __syncthreads();

    zout[(size_t)r * DDIM + j]       = zrow[j];
    zout[(size_t)r * DDIM + 128 + j] = zrow[128 + j];
    if (xaN) xaN[(size_t)r * ADIM + j] = (_Float16)zrow[permN[iaN[j]]];
    if (j == 0) ldout[r] = (first ? 0.f : ldin[r]) + part[0] + part[1];
}

// ---------------------------------------------------------------------------
extern "C" void kernel_launch(void* const* d_in, const int* in_sizes, int n_in,
                              void* d_out, int out_size, void* d_ws, size_t ws_size,
                              hipStream_t stream)
{
    const float* x    = (const float*)d_in[0];
    const float* ctx  = (const float*)d_in[1];
    const float* temb = (const float*)d_in[2];
    const float* cemb = (const float*)d_in[3];
    const float* W1   = (const float*)d_in[4];
    const float* b1   = (const float*)d_in[5];
    const float* W2   = (const float*)d_in[6];
    const float* b2   = (const float*)d_in[7];
    const float* W3   = (const float*)d_in[8];
    const float* b3   = (const float*)d_in[9];
    const float* Ws   = (const float*)d_in[10];
    const float* bs   = (const float*)d_in[11];
    const float* Wt   = (const float*)d_in[12];
    const float* bt   = (const float*)d_in[13];
    const int*   perm = (const int*)d_in[14];
    const int*   idxa = (const int*)d_in[15];
    const int*   idxb = (const int*)d_in[16];

    float* out_z  = (float*)d_out;
    float* out_ld = out_z + (size_t)BROWS * DDIM;

    // ---- workspace layout (with lifetime-based aliasing, ~280 MB peak) ----
    _Float16* W1at = (_Float16*)d_ws;                                 // 1 M f16
    _Float16* W2t  = W1at + (size_t)L_LAYERS * HDIM * ADIM;           // 8 M
    _Float16* W3t  = W2t  + (size_t)L_LAYERS * HDIM * HDIM;           // 8 M
    _Float16* WsWtT= W3t  + (size_t)L_LAYERS * HDIM * HDIM;           // 2 M
    _Float16* xa   = WsWtT+ (size_t)L_LAYERS * 256 * HDIM;            // 1 M
    _Float16* hB   = xa   + (size_t)BROWS * ADIM;                     // 8 M
    _Float16* pre  = hB   + (size_t)BROWS * HDIM;                     // 64 M
    float* biasSS  = (float*)(pre + (size_t)BROWS * L_LAYERS * HDIM); // 2 K f32
    // cte region (24 M f16): dead after big GEMM -> hA aliases it
    _Float16* cte  = (_Float16*)(biasSS + L_LAYERS * 256);
    _Float16* hA   = cte;
    // W1ct region (24 M f16): dead after big GEMM -> fp32 temporaries alias it
    _Float16* W1ct = cte + (size_t)BROWS * CTEDIM;
    float* ssbuf   = (float*)W1ct;                                    // B*256
    float* z0      = ssbuf + (size_t)BROWS * DDIM;
    float* z1      = z0    + (size_t)BROWS * DDIM;
    float* ldacc   = z1    + (size_t)BROWS * DDIM;                    // B

    // ---- setup: weight transposes (fp32 -> f16, K x N -> N x K) ----
    transpose_to_f16<<<dim3(HDIM / 64, ADIM / 64, L_LAYERS), 256, 0, stream>>>(
        W1, W1at, ADIM, HDIM, (size_t)INDIM * HDIM, (size_t)HDIM * ADIM);
    transpose_to_f16<<<dim3(HDIM / 64, CTEDIM / 64, L_LAYERS), 256, 0, stream>>>(
        W1 + (size_t)ADIM * HDIM, W1ct, CTEDIM, HDIM,
        (size_t)INDIM * HDIM, (size_t)HDIM * CTEDIM);
    transpose_to_f16<<<dim3(HDIM / 64, HDIM / 64, L_LAYERS), 256, 0, stream>>>(
        W2, W2t, HDIM, HDIM, (size_t)HDIM * HDIM, (size_t)HDIM * HDIM);
    transpose_to_f16<<<dim3(HDIM / 64, HDIM / 64, L_LAYERS), 256, 0, stream>>>(
        W3, W3t, HDIM, HDIM, (size_t)HDIM * HDIM, (size_t)HDIM * HDIM);
    transpose_to_f16<<<dim3(BDIM_ / 64, HDIM / 64, L_LAYERS), 256, 0, stream>>>(
        Ws, WsWtT, HDIM, BDIM_, (size_t)HDIM * BDIM_, (size_t)256 * HDIM);
    transpose_to_f16<<<dim3(BDIM_ / 64, HDIM / 64, L_LAYERS), 256, 0, stream>>>(
        Wt, WsWtT + (size_t)BDIM_ * HDIM, HDIM, BDIM_, (size_t)HDIM * BDIM_, (size_t)256 * HDIM);

    build_cte<<<(BROWS * (CTEDIM / 4)) / 256, 256, 0, stream>>>(ctx, temb, cemb, cte);
    build_biasSS<<<L_LAYERS, 256, 0, stream>>>(bs, bt, biasSS);
    gather_xa0<<<BROWS, 128, 0, stream>>>(x, perm, idxa, xa);

    // ---- big layer-invariant GEMM: pre = cte @ W1c (all 8 layers at once) ----
    gemm8p<0><<<dim3(32 * 32), 512, 0, stream>>>(
        cte, CTEDIM, W1ct, CTEDIM, nullptr, pre, L_LAYERS * HDIM, CTEDIM, 32);

    // ---- 8 coupling layers ----
    const float* zin = x;
    for (int l = 0; l < L_LAYERS; ++l) {
        const _Float16* w1a = W1at + (size_t)l * HDIM * ADIM;
        const _Float16* w2  = W2t  + (size_t)l * HDIM * HDIM;
        const _Float16* w3  = W3t  + (size_t)l * HDIM * HDIM;
        const _Float16* w4  = WsWtT+ (size_t)l * 256 * HDIM;

        // GEMM1': silu(xa @ W1a + pre[:, l*H:(l+1)*H] + b1) -> hA
        gemm_mfma<0><<<dim3(HDIM / 128, BROWS / 128), 256, 0, stream>>>(
            xa, ADIM, w1a, ADIM, b1 + (size_t)l * HDIM,
            pre + (size_t)l * HDIM, L_LAYERS * HDIM,
            hA, nullptr, HDIM, ADIM);
        // GEMM2: silu(hA @ W2 + b2) -> hB
        gemm8p<1><<<dim3(128), 512, 0, stream>>>(
            hA, HDIM, w2, HDIM, b2 + (size_t)l * HDIM, hB, HDIM, HDIM, 4);
        // GEMM3: silu(hB @ W3 + b3) -> hA
        gemm8p<1><<<dim3(128), 512, 0, stream>>>(
            hB, HDIM, w3, HDIM, b3 + (size_t)l * HDIM, hA, HDIM, HDIM, 4);
        // GEMM4: hA @ [Ws|Wt] + bias -> fp32 ss
        gemm_mfma<1><<<dim3(256 / 128, BROWS / 128), 256, 0, stream>>>(
            hA, HDIM, w4, HDIM, biasSS + (size_t)l * 256,
            nullptr, 0, nullptr, ssbuf, 256, HDIM);

        // epilogue
        float* zout = (l == L_LAYERS - 1) ? out_z : ((l & 1) ? z1 : z0);
        const int last = (l == L_LAYERS - 1);
        coupling_ep<<<BROWS, 128, 0, stream>>>(
            zin, ssbuf,
            perm + (size_t)l * DDIM, idxa + (size_t)l * ADIM, idxb + (size_t)l * ADIM,
            last ? nullptr : perm + (size_t)(l + 1) * DDIM,
            last ? nullptr : idxa + (size_t)(l + 1) * ADIM,
            zout, last ? nullptr : xa,
            ldacc, last ? out_ld : ldacc, l == 0);
        zin = zout;
    }
}

// Round 4
// 1328.645 us; speedup vs baseline: 1.3606x; 1.1446x over previous
//
#include <hip/hip_runtime.h>

// ---------------------------------------------------------------------------
// ConditionalRealNVP on MI355X.
// Layer-invariant ctx-part of GEMM1 hoisted into ONE 8192x8192x3072 GEMM.
// All big GEMMs use a 256xBN 8-phase counted-vmcnt MFMA template (T3+T4+T5)
// with pre-swizzled-source LDS (T2, rule #21) and 2-D XCD region swizzle:
//   BN=256 for the hoisted GEMM (grid 32x32, 16x8 region per XCD)
//   BN=128 for GEMM2/3      (grid 32x8 = 256 wgs = full machine, 8x4 region)
// Counted vmcnt gate is BEFORE the tile's final barrier (round-3 race fix).
// ---------------------------------------------------------------------------

#define L_LAYERS 8
#define DDIM     256
#define HDIM     1024
#define BROWS    8192
#define ADIM     128          // D/2
#define BDIM_    128          // D - A
#define INDIM    3200         // A + 3*H
#define CTEDIM   3072         // 3*H
#define CLIPV    3.0f

typedef _Float16 f16x8 __attribute__((ext_vector_type(8)));
typedef _Float16 f16x4 __attribute__((ext_vector_type(4)));
typedef float    f32x4 __attribute__((ext_vector_type(4)));

__device__ __forceinline__ void async_copy16(const _Float16* g, _Float16* s) {
    __builtin_amdgcn_global_load_lds((const __attribute__((address_space(1))) void*)g,
                                     (__attribute__((address_space(3))) void*)s,
                                     16, 0, 0);
}

// ---------------------------------------------------------------------------
// 256xBN 8-phase template GEMM: C = act(A @ Bt^T + bias)
// A row-major MxK f16, Bt row-major NxK f16.  512 threads / 8 waves.
// BK=64 as two k-halves of 32; per operand a 4-half-slot LDS ring
// (A slot [256][32] f16 = 16KB, B slot [BN][32] f16).  LDS written linearly
// by global_load_lds; quarter swizzle applied by permuting the GLOBAL source
// and undone on the read side (conflict-free ds_read_b128).
// Counted vmcnt gate once per K-tile BEFORE its final barrier.
// Workgroup swizzle: 8 XCD regions of rr x RC blocks (L2 panel reuse).
// MODE 0: raw f16 store.  MODE 1: bias + silu -> f16.
// ---------------------------------------------------------------------------
template <int MODE, int BN>
__global__ __launch_bounds__(512, 2)
void gemm8p(const _Float16* __restrict__ A, int lda,
            const _Float16* __restrict__ Bt, int ldb,
            const float* __restrict__ bias,
            _Float16* __restrict__ C, int ldc,
            int K, int gx, int RC, int rr)
{
    constexpr int MR = (BN == 256) ? 8 : 4;            // M fragments per wave
    constexpr int BSLOT = BN * 32;                     // f16 per B half-slot
    __shared__ __attribute__((aligned(16))) _Float16 lds[32768 + 4 * BSLOT];

    const int tid  = threadIdx.x;
    const int w    = tid >> 6, lane = tid & 63;

    // ---- 2-D XCD region swizzle: xcd = bid&7 owns an rr x RC block region --
    const int bid = blockIdx.x;
    const int xcd = bid & 7, idx = bid >> 3;
    const int rpx = gx / RC;
    const int by  = (xcd / rpx) * rr + idx / RC;
    const int bx  = (xcd % rpx) * RC + idx % RC;
    const int m0  = by << 8, n0 = bx * BN;

    const int NT = K >> 6;   // K-tiles (K >= 128)

    // staging: thread covers row tid>>2 (and +128 for A / BN=256 B);
    // source quarter pre-swizzled so the LINEAR LDS write realizes the
    // XOR-swizzled layout:  LDS[row][q] = src[row][ q ^ ((row>>1)&3) ].
    const int srow = tid >> 2;
    const int srcq = ((tid & 3) ^ ((tid >> 3) & 3)) * 8;     // f16 offset
    const _Float16* gA = A  + (size_t)(m0 + srow) * lda + srcq;
    const _Float16* gB = Bt + (size_t)(n0 + srow) * ldb + srcq;
    const size_t a128 = (size_t)128 * lda;
    const size_t b128 = (size_t)128 * ldb;
    _Float16* ldsA = lds + w * 512;            // wave-uniform stage bases
    _Float16* ldsB = lds + 32768 + w * 512;

#define STG_A(t_, kh_) do { if ((t_) < NT) { \
        const _Float16* s_ = gA + (size_t)(t_) * 64 + (kh_) * 32; \
        _Float16* d_ = ldsA + (((2 * (t_) + (kh_)) & 3) * 8192); \
        async_copy16(s_, d_); async_copy16(s_ + a128, d_ + 4096); } } while (0)
#define STG_B(t_, kh_) do { if ((t_) < NT) { \
        const _Float16* s_ = gB + (size_t)(t_) * 64 + (kh_) * 32; \
        _Float16* d_ = ldsB + (((2 * (t_) + (kh_)) & 3) * BSLOT); \
        async_copy16(s_, d_); \
        if (BN == 256) async_copy16(s_ + b128, d_ + 4096); } } while (0)

    f32x4 acc[MR][4];
#pragma unroll
    for (int i = 0; i < MR; ++i)
#pragma unroll
        for (int j = 0; j < 4; ++j) acc[i][j] = (f32x4){0.f, 0.f, 0.f, 0.f};

    // prologue: tile0 complete + tile1 kh0
    STG_A(0, 0); STG_B(0, 0); STG_A(0, 1); STG_B(0, 1);
    STG_A(1, 0); STG_B(1, 0);
    if (BN == 256) { asm volatile("s_waitcnt vmcnt(4)" ::: "memory"); }
    else           { asm volatile("s_waitcnt vmcnt(3)" ::: "memory"); }
    __builtin_amdgcn_s_barrier();

    // read-side swizzle: per-lane constant quarter XOR
    const int qsw = ((lane & 15) >> 1) & 3;
    const int q16 = ((lane >> 4) ^ qsw) << 4;              // byte offset
    const int rA0 = (BN == 256) ? ((w >> 2) * 128 + (lane & 15))
                                : ((w >> 1) * 64  + (lane & 15));
    const int rA1 = rA0 + 64;                               // BN=256 only
    const int rB  = (BN == 256) ? ((w & 3) * 64 + (lane & 15))
                                : ((w & 1) * 64 + (lane & 15));
    const char* ldsc = (const char*)&lds[0];

    f16x8 bf[4];

#define LOADB(slB) { _Pragma("unroll") for (int f = 0; f < 4; ++f) \
        bf[f] = *(const f16x8*)(ldsc + 65536 + (slB) + (rB + f * 16) * 64 + q16); }
#define LOADA(slA, rb_) { _Pragma("unroll") for (int f = 0; f < 4; ++f) \
        af[f] = *(const f16x8*)(ldsc + (slA) + ((rb_) + f * 16) * 64 + q16); }
#define MFMA16(mo) { __builtin_amdgcn_s_setprio(1); \
        _Pragma("unroll") for (int f = 0; f < 4; ++f) \
        _Pragma("unroll") for (int nf = 0; nf < 4; ++nf) \
            acc[(mo) + f][nf] = __builtin_amdgcn_mfma_f32_16x16x32_f16(af[f], bf[nf], acc[(mo) + f][nf], 0, 0, 0); \
        __builtin_amdgcn_s_setprio(0); }
#define BAR() __builtin_amdgcn_s_barrier()
#define LGKM0() do { asm volatile("s_waitcnt lgkmcnt(0)" ::: "memory"); \
        __builtin_amdgcn_sched_barrier(0); } while (0)

    for (int T = 0; T < NT; ++T) {
        const int sA0 = ((2 * T) & 3) << 14;         // A slot byte offsets
        const int sA1 = ((2 * T + 1) & 3) << 14;
        const int sB0 = ((2 * T) & 3) * (BSLOT * 2); // B slot byte offsets
        const int sB1 = ((2 * T + 1) & 3) * (BSLOT * 2);

        if (BN == 256) {
            { f16x8 af[4]; LOADB(sB0); LOADA(sA0, rA0); STG_A(T + 1, 1);
              BAR(); LGKM0(); MFMA16(0); BAR(); }
            { f16x8 af[4]; LOADA(sA0, rA1); STG_B(T + 1, 1);
              BAR(); LGKM0(); MFMA16(4); BAR(); }
            { f16x8 af[4]; LOADB(sB1); LOADA(sA1, rA0); STG_A(T + 2, 0);
              BAR(); LGKM0(); MFMA16(0); BAR(); }
            { f16x8 af[4]; LOADA(sA1, rA1); STG_B(T + 2, 0);
              BAR(); LGKM0(); MFMA16(4);
              // residency gate for tile T+1, BEFORE the barrier (race fix)
              if (T + 2 < NT) { asm volatile("s_waitcnt vmcnt(4)" ::: "memory"); }
              else            { asm volatile("s_waitcnt vmcnt(0)" ::: "memory"); }
              BAR(); }
        } else {
            { f16x8 af[4]; LOADB(sB0); LOADA(sA0, rA0); STG_A(T + 1, 1); STG_B(T + 1, 1);
              BAR(); LGKM0(); MFMA16(0); BAR(); }
            { f16x8 af[4]; LOADB(sB1); LOADA(sA1, rA0); STG_A(T + 2, 0); STG_B(T + 2, 0);
              BAR(); LGKM0(); MFMA16(0);
              if (T + 2 < NT) { asm volatile("s_waitcnt vmcnt(3)" ::: "memory"); }
              else            { asm volatile("s_waitcnt vmcnt(0)" ::: "memory"); }
              BAR(); }
        }
    }

    // epilogue: C/D layout col = lane&15, row = (lane>>4)*4 + reg
    const int cn = lane & 15, rb4 = (lane >> 4) * 4;
    const int wmOff = (BN == 256) ? (w >> 2) * 128 : (w >> 1) * 64;
    const int wnOff = (BN == 256) ? (w & 3) * 64 : (w & 1) * 64;
#pragma unroll
    for (int i = 0; i < MR; ++i) {
        const int gm = m0 + wmOff + i * 16 + rb4;
#pragma unroll
        for (int j = 0; j < 4; ++j) {
            const int gn = n0 + wnOff + j * 16 + cn;
            const float bv = (MODE == 1) ? bias[gn] : 0.f;
#pragma unroll
            for (int r = 0; r < 4; ++r) {
                float v = acc[i][j][r] + bv;
                if (MODE == 1) v = v / (1.f + __expf(-v));
                C[(size_t)(gm + r) * ldc + gn] = (_Float16)v;
            }
        }
    }
#undef STG_A
#undef STG_B
#undef LOADB
#undef LOADA
#undef MFMA16
#undef BAR
#undef LGKM0
}

// ---------------------------------------------------------------------------
// 128x128 m97-style GEMM for small shapes (GEMM1' K=128 w/ pre-add, GEMM4).
// Pre-swizzled-source LDS ([128][64] f16).  MODE 0: silu(acc+bias+pre)->f16.
// MODE 1: acc+bias->fp32.
// ---------------------------------------------------------------------------
template <int MODE>
__global__ __launch_bounds__(256)
void gemm_mfma(const _Float16* __restrict__ A0, int lda0,
               const _Float16* __restrict__ Bt, int ldb,
               const float* __restrict__ bias,
               const _Float16* __restrict__ preadd, int ldpre,
               _Float16* __restrict__ Hout,
               float* __restrict__ Fout,
               int N, int K)
{
    __shared__ __attribute__((aligned(16))) _Float16 As[128 * 64];
    __shared__ __attribute__((aligned(16))) _Float16 Bs[128 * 64];

    const int tid  = threadIdx.x;
    const int wave = tid >> 6;
    const int lane = tid & 63;
    const int m0 = blockIdx.y * 128;
    const int n0 = blockIdx.x * 128;
    const int wm = (wave >> 1) * 64;
    const int wn = (wave & 1) * 64;

    f32x4 acc[4][4];
#pragma unroll
    for (int i = 0; i < 4; ++i)
#pragma unroll
        for (int j = 0; j < 4; ++j)
            acc[i][j] = (f32x4){0.f, 0.f, 0.f, 0.f};

    const int rsub = lane >> 3;
    const int csub = ((lane & 7) ^ (lane >> 3)) * 8;   // pre-swizzled source quarter

    for (int k0 = 0; k0 < K; k0 += 64) {
#pragma unroll
        for (int i = 0; i < 4; ++i) {
            const int row = i * 32 + wave * 8 + rsub;
            async_copy16(A0 + (size_t)(m0 + row) * lda0 + k0 + csub,
                         &As[(i * 32 + wave * 8) * 64]);
        }
#pragma unroll
        for (int i = 0; i < 4; ++i) {
            const int row = i * 32 + wave * 8 + rsub;
            async_copy16(Bt + (size_t)(n0 + row) * ldb + k0 + csub,
                         &Bs[(i * 32 + wave * 8) * 64]);
        }
        __syncthreads();   // full drain + barrier

#pragma unroll
        for (int kk = 0; kk < 2; ++kk) {
            const int c = ((kk * 4 + (lane >> 4)) ^ (lane & 7)) * 8;  // swizzled read
            f16x8 af[4], bfr[4];
#pragma unroll
            for (int i = 0; i < 4; ++i) {
                af[i]  = *(const f16x8*)&As[(wm + i * 16 + (lane & 15)) * 64 + c];
                bfr[i] = *(const f16x8*)&Bs[(wn + i * 16 + (lane & 15)) * 64 + c];
            }
#pragma unroll
            for (int i = 0; i < 4; ++i)
#pragma unroll
                for (int j = 0; j < 4; ++j)
                    acc[i][j] = __builtin_amdgcn_mfma_f32_16x16x32_f16(af[i], bfr[j], acc[i][j], 0, 0, 0);
        }
        __syncthreads();
    }

    const int cn = lane & 15;
    const int rb = (lane >> 4) * 4;
#pragma unroll
    for (int j = 0; j < 4; ++j) {
        const int gn = n0 + wn + j * 16 + cn;
        const float bv = bias[gn];
#pragma unroll
        for (int i = 0; i < 4; ++i) {
            const int gm0 = m0 + wm + i * 16 + rb;
#pragma unroll
            for (int r = 0; r < 4; ++r) {
                float v = acc[i][j][r] + bv;
                if (MODE == 0) {
                    v += (float)preadd[(size_t)(gm0 + r) * ldpre + gn];
                    const float s = v / (1.f + __expf(-v));
                    Hout[(size_t)(gm0 + r) * N + gn] = (_Float16)s;
                } else {
                    Fout[(size_t)(gm0 + r) * N + gn] = v;
                }
            }
        }
    }
}

// ---------------------------------------------------------------------------
// Transpose + fp32 -> f16: in (K x N) row-major fp32 -> out (N x K) f16.
// ---------------------------------------------------------------------------
__global__ void transpose_to_f16(const float* __restrict__ in, _Float16* __restrict__ out,
                                 int K, int N, size_t inLayerStride, size_t outLayerStride)
{
    __shared__ float t[64][65];
    in  += (size_t)blockIdx.z * inLayerStride;
    out += (size_t)blockIdx.z * outLayerStride;
    const int kb = blockIdx.y * 64, nb = blockIdx.x * 64;
    const int tx = threadIdx.x & 63, ty = threadIdx.x >> 6;
#pragma unroll
    for (int i = 0; i < 64; i += 4)
        t[ty + i][tx] = in[(size_t)(kb + ty + i) * N + nb + tx];
    __syncthreads();
#pragma unroll
    for (int i = 0; i < 64; i += 4)
        out[(size_t)(nb + ty + i) * K + kb + tx] = (_Float16)t[tx][ty + i];
}

// concat(ctx, t_emb, cond_emb) -> f16, B x 3072
__global__ void build_cte(const float* __restrict__ ctx, const float* __restrict__ te,
                          const float* __restrict__ ce, _Float16* __restrict__ out)
{
    const int idx = blockIdx.x * blockDim.x + threadIdx.x;   // over B*768
    const int r = idx / (CTEDIM / 4);
    const int c = (idx % (CTEDIM / 4)) * 4;
    const float* src = (c < 1024) ? ctx + (size_t)r * 1024 + c
                     : (c < 2048) ? te  + (size_t)r * 1024 + (c - 1024)
                                  : ce  + (size_t)r * 1024 + (c - 2048);
    const float4 v = *reinterpret_cast<const float4*>(src);
    f16x4 o; o.x = (_Float16)v.x; o.y = (_Float16)v.y; o.z = (_Float16)v.z; o.w = (_Float16)v.w;
    *reinterpret_cast<f16x4*>(&out[idx * 4]) = o;
}

__global__ void build_biasSS(const float* __restrict__ bs, const float* __restrict__ bt,
                             float* __restrict__ out)
{
    const int id = blockIdx.x * 256 + threadIdx.x;   // L*256
    const int l = id >> 8, j = id & 255;
    out[id] = (j < 128) ? bs[l * 128 + j] : bt[l * 128 + (j - 128)];
}

__global__ void gather_xa0(const float* __restrict__ x, const int* __restrict__ perm,
                           const int* __restrict__ ia, _Float16* __restrict__ xa)
{
    const int r = blockIdx.x, j = threadIdx.x;   // 128 threads
    xa[(size_t)r * ADIM + j] = (_Float16)x[(size_t)r * DDIM + perm[ia[j]]];
}

// ---------------------------------------------------------------------------
// Coupling epilogue (1 row / 128-thread block); fuses next layer's x_a gather.
// ---------------------------------------------------------------------------
__global__ void coupling_ep(const float* __restrict__ zin,
                            const float* __restrict__ ss,
                            const int* __restrict__ perm,
                            const int* __restrict__ ia_,
                            const int* __restrict__ ib_,
                            const int* __restrict__ permN,
                            const int* __restrict__ iaN,
                            float* __restrict__ zout,
                            _Float16* __restrict__ xaN,
                            const float* __restrict__ ldin,
                            float* __restrict__ ldout,
                            int first)
{
    const int r = blockIdx.x, j = threadIdx.x;   // j in [0,128)
    __shared__ float zrow[DDIM];
    __shared__ float part[2];

    const int ia = ia_[j], ib = ib_[j];
    const float xav = zin[(size_t)r * DDIM + perm[ia]];
    const float xbv = zin[(size_t)r * DDIM + perm[ib]];
    float sc = ss[(size_t)r * DDIM + j];
    sc = fminf(CLIPV, fmaxf(-CLIPV, sc));
    const float sh = ss[(size_t)r * DDIM + 128 + j];
    const float yb = xbv * __expf(sc) + sh;

    zrow[ia] = xav;
    zrow[ib] = yb;

    float v = sc;
#pragma unroll
    for (int off = 32; off; off >>= 1) v += __shfl_down(v, off, 64);
    if ((j & 63) == 0) part[j >> 6] = v;
    __syncthreads();

    zout[(size_t)r * DDIM + j]       = zrow[j];
    zout[(size_t)r * DDIM + 128 + j] = zrow[128 + j];
    if (xaN) xaN[(size_t)r * ADIM + j] = (_Float16)zrow[permN[iaN[j]]];
    if (j == 0) ldout[r] = (first ? 0.f : ldin[r]) + part[0] + part[1];
}

// ---------------------------------------------------------------------------
extern "C" void kernel_launch(void* const* d_in, const int* in_sizes, int n_in,
                              void* d_out, int out_size, void* d_ws, size_t ws_size,
                              hipStream_t stream)
{
    const float* x    = (const float*)d_in[0];
    const float* ctx  = (const float*)d_in[1];
    const float* temb = (const float*)d_in[2];
    const float* cemb = (const float*)d_in[3];
    const float* W1   = (const float*)d_in[4];
    const float* b1   = (const float*)d_in[5];
    const float* W2   = (const float*)d_in[6];
    const float* b2   = (const float*)d_in[7];
    const float* W3   = (const float*)d_in[8];
    const float* b3   = (const float*)d_in[9];
    const float* Ws   = (const float*)d_in[10];
    const float* bs   = (const float*)d_in[11];
    const float* Wt   = (const float*)d_in[12];
    const float* bt   = (const float*)d_in[13];
    const int*   perm = (const int*)d_in[14];
    const int*   idxa = (const int*)d_in[15];
    const int*   idxb = (const int*)d_in[16];

    float* out_z  = (float*)d_out;
    float* out_ld = out_z + (size_t)BROWS * DDIM;

    // ---- workspace layout (lifetime-based aliasing) ----
    _Float16* W1at = (_Float16*)d_ws;                                 // 1 M f16
    _Float16* W2t  = W1at + (size_t)L_LAYERS * HDIM * ADIM;           // 8 M
    _Float16* W3t  = W2t  + (size_t)L_LAYERS * HDIM * HDIM;           // 8 M
    _Float16* WsWtT= W3t  + (size_t)L_LAYERS * HDIM * HDIM;           // 2 M
    _Float16* xa   = WsWtT+ (size_t)L_LAYERS * 256 * HDIM;            // 1 M
    _Float16* hB   = xa   + (size_t)BROWS * ADIM;                     // 8 M
    _Float16* pre  = hB   + (size_t)BROWS * HDIM;                     // 64 M
    float* biasSS  = (float*)(pre + (size_t)BROWS * L_LAYERS * HDIM); // 2 K f32
    // cte region (24 M f16): dead after big GEMM -> hA aliases it
    _Float16* cte  = (_Float16*)(biasSS + L_LAYERS * 256);
    _Float16* hA   = cte;
    // W1ct region (24 M f16): dead after big GEMM -> fp32 temporaries alias it
    _Float16* W1ct = cte + (size_t)BROWS * CTEDIM;
    float* ssbuf   = (float*)W1ct;                                    // B*256
    float* z0      = ssbuf + (size_t)BROWS * DDIM;
    float* z1      = z0    + (size_t)BROWS * DDIM;
    float* ldacc   = z1    + (size_t)BROWS * DDIM;                    // B

    // ---- setup: weight transposes (fp32 -> f16, K x N -> N x K) ----
    transpose_to_f16<<<dim3(HDIM / 64, ADIM / 64, L_LAYERS), 256, 0, stream>>>(
        W1, W1at, ADIM, HDIM, (size_t)INDIM * HDIM, (size_t)HDIM * ADIM);
    transpose_to_f16<<<dim3(HDIM / 64, CTEDIM / 64, L_LAYERS), 256, 0, stream>>>(
        W1 + (size_t)ADIM * HDIM, W1ct, CTEDIM, HDIM,
        (size_t)INDIM * HDIM, (size_t)HDIM * CTEDIM);
    transpose_to_f16<<<dim3(HDIM / 64, HDIM / 64, L_LAYERS), 256, 0, stream>>>(
        W2, W2t, HDIM, HDIM, (size_t)HDIM * HDIM, (size_t)HDIM * HDIM);
    transpose_to_f16<<<dim3(HDIM / 64, HDIM / 64, L_LAYERS), 256, 0, stream>>>(
        W3, W3t, HDIM, HDIM, (size_t)HDIM * HDIM, (size_t)HDIM * HDIM);
    transpose_to_f16<<<dim3(BDIM_ / 64, HDIM / 64, L_LAYERS), 256, 0, stream>>>(
        Ws, WsWtT, HDIM, BDIM_, (size_t)HDIM * BDIM_, (size_t)256 * HDIM);
    transpose_to_f16<<<dim3(BDIM_ / 64, HDIM / 64, L_LAYERS), 256, 0, stream>>>(
        Wt, WsWtT + (size_t)BDIM_ * HDIM, HDIM, BDIM_, (size_t)HDIM * BDIM_, (size_t)256 * HDIM);

    build_cte<<<(BROWS * (CTEDIM / 4)) / 256, 256, 0, stream>>>(ctx, temb, cemb, cte);
    build_biasSS<<<L_LAYERS, 256, 0, stream>>>(bs, bt, biasSS);
    gather_xa0<<<BROWS, 128, 0, stream>>>(x, perm, idxa, xa);

    // ---- big layer-invariant GEMM: pre = cte @ W1c (grid 32x32, 16x8/XCD) --
    gemm8p<0, 256><<<dim3(1024), 512, 0, stream>>>(
        cte, CTEDIM, W1ct, CTEDIM, nullptr, pre, L_LAYERS * HDIM, CTEDIM,
        /*gx*/32, /*RC*/8, /*rr*/16);

    // ---- 8 coupling layers ----
    const float* zin = x;
    for (int l = 0; l < L_LAYERS; ++l) {
        const _Float16* w1a = W1at + (size_t)l * HDIM * ADIM;
        const _Float16* w2  = W2t  + (size_t)l * HDIM * HDIM;
        const _Float16* w3  = W3t  + (size_t)l * HDIM * HDIM;
        const _Float16* w4  = WsWtT+ (size_t)l * 256 * HDIM;

        // GEMM1': silu(xa @ W1a + pre[:, l*H:(l+1)*H] + b1) -> hA
        gemm_mfma<0><<<dim3(HDIM / 128, BROWS / 128), 256, 0, stream>>>(
            xa, ADIM, w1a, ADIM, b1 + (size_t)l * HDIM,
            pre + (size_t)l * HDIM, L_LAYERS * HDIM,
            hA, nullptr, HDIM, ADIM);
        // GEMM2: silu(hA @ W2 + b2) -> hB   (grid 32x8 = 256 wgs, 8x4/XCD)
        gemm8p<1, 128><<<dim3(256), 512, 0, stream>>>(
            hA, HDIM, w2, HDIM, b2 + (size_t)l * HDIM, hB, HDIM, HDIM,
            /*gx*/8, /*RC*/4, /*rr*/8);
        // GEMM3: silu(hB @ W3 + b3) -> hA
        gemm8p<1, 128><<<dim3(256), 512, 0, stream>>>(
            hB, HDIM, w3, HDIM, b3 + (size_t)l * HDIM, hA, HDIM, HDIM,
            /*gx*/8, /*RC*/4, /*rr*/8);
        // GEMM4: hA @ [Ws|Wt] + bias -> fp32 ss
        gemm_mfma<1><<<dim3(256 / 128, BROWS / 128), 256, 0, stream>>>(
            hA, HDIM, w4, HDIM, biasSS + (size_t)l * 256,
            nullptr, 0, nullptr, ssbuf, 256, HDIM);

        // epilogue
        float* zout = (l == L_LAYERS - 1) ? out_z : ((l & 1) ? z1 : z0);
        const int last = (l == L_LAYERS - 1);
        coupling_ep<<<BROWS, 128, 0, stream>>>(
            zin, ssbuf,
            perm + (size_t)l * DDIM, idxa + (size_t)l * ADIM, idxb + (size_t)l * ADIM,
            last ? nullptr : perm + (size_t)(l + 1) * DDIM,
            last ? nullptr : idxa + (size_t)(l + 1) * ADIM,
            zout, last ? nullptr : xa,
            ldacc, last ? out_ld : ldacc, l == 0);
        zin = zout;
    }
}

// Round 7
// 1327.313 us; speedup vs baseline: 1.3619x; 1.0010x over previous
//
#include <hip/hip_runtime.h>

// ---------------------------------------------------------------------------
// ConditionalRealNVP on MI355X.
// Layer-invariant ctx-part of GEMM1 hoisted into ONE 8192x8192x3072 GEMM.
// Big GEMMs: 256xBN MFMA template, 2 merged phases per K-tile (32/16 MFMA per
// phase, ONE lgkmcnt(0) per phase covering all 12/8 ds_reads), counted vmcnt
// gates per re-derived 4-load-group ledger, 2-D XCD region swizzle.
// ROUND-7 FIX vs rounds 5/6: staging uses global_load_lds with offset=0 and
// pointer-folded k-offsets (round-4-proven semantics).  The imm-offset arg of
// global_load_lds is UNVERIFIED on gfx950 (may shift the LDS destination) and
// was the lone mechanism shared by the two NaN rounds.
// ---------------------------------------------------------------------------

#define L_LAYERS 8
#define DDIM     256
#define HDIM     1024
#define BROWS    8192
#define ADIM     128          // D/2
#define BDIM_    128          // D - A
#define INDIM    3200         // A + 3*H
#define CTEDIM   3072         // 3*H
#define CLIPV    3.0f

typedef _Float16 f16x8 __attribute__((ext_vector_type(8)));
typedef _Float16 f16x4 __attribute__((ext_vector_type(4)));
typedef float    f32x4 __attribute__((ext_vector_type(4)));

__device__ __forceinline__ void async_copy16(const _Float16* g, _Float16* s) {
    __builtin_amdgcn_global_load_lds((const __attribute__((address_space(1))) void*)g,
                                     (__attribute__((address_space(3))) void*)s,
                                     16, 0, 0);
}

// ---------------------------------------------------------------------------
// 256xBN template GEMM: C = act(A @ Bt^T + bias)
// A row-major MxK f16, Bt row-major NxK f16.  512 threads / 8 waves.
// BK=64 as two k-halves of 32; 4-half-slot LDS ring per operand
// (A slot [256][32] f16 = 16KB, B slot [BN][32]).  LDS written linearly by
// global_load_lds; quarter swizzle via pre-permuted GLOBAL source, undone by
// per-lane-constant XOR on the read side (conflict-free ds_read_b128).
//
// Ledger (stage group = one (tile,kh) A+B stage; 4 loads BN=256, 3 BN=128):
// entry-of-tile pending = {g(T,1), g(T+1,0)}.  Each phase stages one group
// (pending -> 12/9) and gates vmcnt(8)/vmcnt(6) BEFORE its end barrier,
// draining exactly the group the NEXT phase reads.  When the staged tile
// doesn't exist the gate is vmcnt(0).  All lgkm waits are lgkmcnt(0)
// (order-independent under any compiler scheduling of the ds_reads).
// MODE 0: raw f16 store.  MODE 1: bias + silu -> f16.
// ---------------------------------------------------------------------------
template <int MODE, int BN>
__global__ __launch_bounds__(512, 2)
void gemm8p(const _Float16* __restrict__ A, int lda,
            const _Float16* __restrict__ Bt, int ldb,
            const float* __restrict__ bias,
            _Float16* __restrict__ C, int ldc,
            int K, int gx, int RC, int rr)
{
    constexpr int MR     = (BN == 256) ? 8 : 4;    // M fragments per wave
    constexpr int BSLOT  = BN * 32;                // f16 per B half-slot
    constexpr int BSLOTB = BN * 64;                // bytes per B half-slot
    __shared__ __attribute__((aligned(16))) _Float16 lds[32768 + 4 * BSLOT];

    const int tid  = threadIdx.x;
    const int w    = tid >> 6, lane = tid & 63;

    // ---- 2-D XCD region swizzle ----
    const int bid = blockIdx.x;
    const int xcd = bid & 7, idx = bid >> 3;
    const int rpx = gx / RC;
    const int by  = (xcd / rpx) * rr + idx / RC;
    const int bx  = (xcd % rpx) * RC + idx % RC;
    const int m0  = by << 8, n0 = bx * BN;

    const int NT = K >> 6;   // K-tiles; NT >= 4

    // staging: thread covers row tid>>2 (and +128); source quarter
    // pre-swizzled: LDS[row][q] = src[row][ q ^ ((row>>1)&3) ].
    const int srow = tid >> 2;
    const int srcq = ((tid & 3) ^ ((tid >> 3) & 3)) * 8;
    const _Float16* gA = A  + (size_t)(m0 + srow) * lda + srcq;
    const _Float16* gB = Bt + (size_t)(n0 + srow) * ldb + srcq;
    const size_t a128 = (size_t)128 * lda;
    const size_t b128 = (size_t)128 * ldb;
    _Float16* ldsA = lds + w * 512;            // wave-uniform stage bases
    _Float16* ldsB = lds + 32768 + w * 512;

    // one full stage group (tile t_, k-half kh_) -> ring slot (2t+kh)&3
#define STG(t_, kh_) do { if ((t_) < NT) {                                 \
        const _Float16* sa_ = gA + (size_t)(t_) * 64 + (kh_) * 32;         \
        const _Float16* sb_ = gB + (size_t)(t_) * 64 + (kh_) * 32;         \
        const int ss_ = (2 * (t_) + (kh_)) & 3;                            \
        async_copy16(sa_,        ldsA + ss_ * 8192);                       \
        async_copy16(sa_ + a128, ldsA + ss_ * 8192 + 4096);                \
        async_copy16(sb_,        ldsB + ss_ * BSLOT);                      \
        if constexpr (BN == 256)                                           \
            async_copy16(sb_ + b128, ldsB + ss_ * BSLOT + 4096);           \
    } } while (0)

    f32x4 acc[MR][4];
#pragma unroll
    for (int i = 0; i < MR; ++i)
#pragma unroll
        for (int j = 0; j < 4; ++j) acc[i][j] = (f32x4){0.f, 0.f, 0.f, 0.f};

    // ---- prologue: stage g(0,0)->slot0, g(0,1)->slot1, g(1,0)->slot2 ----
    STG(0, 0); STG(0, 1); STG(1, 0);
    if constexpr (BN == 256) { asm volatile("s_waitcnt vmcnt(8)" ::: "memory"); }
    else                     { asm volatile("s_waitcnt vmcnt(6)" ::: "memory"); }
    __builtin_amdgcn_s_barrier();

    // read-side: per-lane constant bases; slot offsets added per phase
    const int qsw = ((lane & 15) >> 1) & 3;
    const int q16 = ((lane >> 4) ^ qsw) << 4;
    const int rA0 = (BN == 256) ? ((w >> 2) * 128 + (lane & 15))
                                : ((w >> 1) * 64  + (lane & 15));
    const int rB  = (BN == 256) ? ((w & 3) * 64 + (lane & 15))
                                : ((w & 1) * 64 + (lane & 15));
    const char* ldsArd = (const char*)lds + (rA0 * 64 + q16);
    const char* ldsBrd = (const char*)lds + 65536 + (rB * 64 + q16);

    // one phase: read slot (2T+KH)&3, stage group (ST_,SKH_), barrier,
    // lgkmcnt(0), MFMA cluster (32 for BN=256, 16 for BN=128), counted gate,
    // barrier.  Gate condition == stage guard (ST_<NT).
#define PHASE(T_, KH_, ST_, SKH_) do {                                         \
    const int sl_ = (2 * (T_) + (KH_)) & 3;                                    \
    f16x8 af[4], ag[4], bf[4];                                                 \
    _Pragma("unroll") for (int f = 0; f < 4; ++f)                              \
        bf[f] = *(const f16x8*)(ldsBrd + sl_ * BSLOTB + f * 1024);             \
    _Pragma("unroll") for (int f = 0; f < 4; ++f)                              \
        af[f] = *(const f16x8*)(ldsArd + sl_ * 16384 + f * 1024);              \
    if constexpr (BN == 256) {                                                 \
        _Pragma("unroll") for (int f = 0; f < 4; ++f)                          \
            ag[f] = *(const f16x8*)(ldsArd + sl_ * 16384 + f * 1024 + 4096);   \
    }                                                                          \
    STG(ST_, SKH_);                                                            \
    __builtin_amdgcn_s_barrier();                                              \
    asm volatile("s_waitcnt lgkmcnt(0)" ::: "memory");                         \
    __builtin_amdgcn_sched_barrier(0);                                         \
    __builtin_amdgcn_s_setprio(1);                                             \
    _Pragma("unroll") for (int f = 0; f < 4; ++f)                              \
    _Pragma("unroll") for (int nf = 0; nf < 4; ++nf)                           \
        acc[f][nf] = __builtin_amdgcn_mfma_f32_16x16x32_f16(af[f], bf[nf], acc[f][nf], 0, 0, 0); \
    if constexpr (BN == 256) {                                                 \
        _Pragma("unroll") for (int f = 0; f < 4; ++f)                          \
        _Pragma("unroll") for (int nf = 0; nf < 4; ++nf)                       \
            acc[4 + f][nf] = __builtin_amdgcn_mfma_f32_16x16x32_f16(ag[f], bf[nf], acc[4 + f][nf], 0, 0, 0); \
    }                                                                          \
    __builtin_amdgcn_s_setprio(0);                                             \
    if ((ST_) < NT) {                                                          \
        if constexpr (BN == 256) { asm volatile("s_waitcnt vmcnt(8)" ::: "memory"); } \
        else                     { asm volatile("s_waitcnt vmcnt(6)" ::: "memory"); } \
    } else { asm volatile("s_waitcnt vmcnt(0)" ::: "memory"); }                \
    __builtin_amdgcn_s_barrier(); } while (0)

    for (int T = 0; T < NT; ++T) {
        PHASE(T, 0, T + 1, 1);   // read (T,0); stage (T+1,1); gate -> (T,1) landed
        PHASE(T, 1, T + 2, 0);   // read (T,1); stage (T+2,0); gate -> (T+1,0) landed
    }
#undef PHASE
#undef STG

    // epilogue: C/D layout col = lane&15, row = (lane>>4)*4 + reg
    const int cn = lane & 15, rb4 = (lane >> 4) * 4;
    const int wmOff = (BN == 256) ? (w >> 2) * 128 : (w >> 1) * 64;
    const int wnOff = (BN == 256) ? (w & 3) * 64 : (w & 1) * 64;
#pragma unroll
    for (int i = 0; i < MR; ++i) {
        const int gm = m0 + wmOff + i * 16 + rb4;
#pragma unroll
        for (int j = 0; j < 4; ++j) {
            const int gn = n0 + wnOff + j * 16 + cn;
            const float bv = (MODE == 1) ? bias[gn] : 0.f;
#pragma unroll
            for (int r = 0; r < 4; ++r) {
                float v = acc[i][j][r] + bv;
                if (MODE == 1) v = v / (1.f + __expf(-v));
                C[(size_t)(gm + r) * ldc + gn] = (_Float16)v;
            }
        }
    }
}

// ---------------------------------------------------------------------------
// 128x128 m97-style GEMM for small shapes (GEMM1' K=128 w/ pre-add, GEMM4).
// Pre-swizzled-source LDS.  MODE 0: silu(acc+bias+pre)->f16.  MODE 1: fp32.
// ---------------------------------------------------------------------------
template <int MODE>
__global__ __launch_bounds__(256)
void gemm_mfma(const _Float16* __restrict__ A0, int lda0,
               const _Float16* __restrict__ Bt, int ldb,
               const float* __restrict__ bias,
               const _Float16* __restrict__ preadd, int ldpre,
               _Float16* __restrict__ Hout,
               float* __restrict__ Fout,
               int N, int K)
{
    __shared__ __attribute__((aligned(16))) _Float16 As[128 * 64];
    __shared__ __attribute__((aligned(16))) _Float16 Bs[128 * 64];

    const int tid  = threadIdx.x;
    const int wave = tid >> 6;
    const int lane = tid & 63;
    const int m0 = blockIdx.y * 128;
    const int n0 = blockIdx.x * 128;
    const int wm = (wave >> 1) * 64;
    const int wn = (wave & 1) * 64;

    f32x4 acc[4][4];
#pragma unroll
    for (int i = 0; i < 4; ++i)
#pragma unroll
        for (int j = 0; j < 4; ++j)
            acc[i][j] = (f32x4){0.f, 0.f, 0.f, 0.f};

    const int rsub = lane >> 3;
    const int csub = ((lane & 7) ^ (lane >> 3)) * 8;

    for (int k0 = 0; k0 < K; k0 += 64) {
#pragma unroll
        for (int i = 0; i < 4; ++i) {
            const int row = i * 32 + wave * 8 + rsub;
            async_copy16(A0 + (size_t)(m0 + row) * lda0 + k0 + csub,
                         &As[(i * 32 + wave * 8) * 64]);
        }
#pragma unroll
        for (int i = 0; i < 4; ++i) {
            const int row = i * 32 + wave * 8 + rsub;
            async_copy16(Bt + (size_t)(n0 + row) * ldb + k0 + csub,
                         &Bs[(i * 32 + wave * 8) * 64]);
        }
        __syncthreads();

#pragma unroll
        for (int kk = 0; kk < 2; ++kk) {
            const int c = ((kk * 4 + (lane >> 4)) ^ (lane & 7)) * 8;
            f16x8 af[4], bfr[4];
#pragma unroll
            for (int i = 0; i < 4; ++i) {
                af[i]  = *(const f16x8*)&As[(wm + i * 16 + (lane & 15)) * 64 + c];
                bfr[i] = *(const f16x8*)&Bs[(wn + i * 16 + (lane & 15)) * 64 + c];
            }
#pragma unroll
            for (int i = 0; i < 4; ++i)
#pragma unroll
                for (int j = 0; j < 4; ++j)
                    acc[i][j] = __builtin_amdgcn_mfma_f32_16x16x32_f16(af[i], bfr[j], acc[i][j], 0, 0, 0);
        }
        __syncthreads();
    }

    const int cn = lane & 15;
    const int rb = (lane >> 4) * 4;
#pragma unroll
    for (int j = 0; j < 4; ++j) {
        const int gn = n0 + wn + j * 16 + cn;
        const float bv = bias[gn];
#pragma unroll
        for (int i = 0; i < 4; ++i) {
            const int gm0 = m0 + wm + i * 16 + rb;
#pragma unroll
            for (int r = 0; r < 4; ++r) {
                float v = acc[i][j][r] + bv;
                if (MODE == 0) {
                    v += (float)preadd[(size_t)(gm0 + r) * ldpre + gn];
                    const float s = v / (1.f + __expf(-v));
                    Hout[(size_t)(gm0 + r) * N + gn] = (_Float16)s;
                } else {
                    Fout[(size_t)(gm0 + r) * N + gn] = v;
                }
            }
        }
    }
}

// ---------------------------------------------------------------------------
__global__ void transpose_to_f16(const float* __restrict__ in, _Float16* __restrict__ out,
                                 int K, int N, size_t inLayerStride, size_t outLayerStride)
{
    __shared__ float t[64][65];
    in  += (size_t)blockIdx.z * inLayerStride;
    out += (size_t)blockIdx.z * outLayerStride;
    const int kb = blockIdx.y * 64, nb = blockIdx.x * 64;
    const int tx = threadIdx.x & 63, ty = threadIdx.x >> 6;
#pragma unroll
    for (int i = 0; i < 64; i += 4)
        t[ty + i][tx] = in[(size_t)(kb + ty + i) * N + nb + tx];
    __syncthreads();
#pragma unroll
    for (int i = 0; i < 64; i += 4)
        out[(size_t)(nb + ty + i) * K + kb + tx] = (_Float16)t[tx][ty + i];
}

__global__ void build_cte(const float* __restrict__ ctx, const float* __restrict__ te,
                          const float* __restrict__ ce, _Float16* __restrict__ out)
{
    const int idx = blockIdx.x * blockDim.x + threadIdx.x;   // over B*768
    const int r = idx / (CTEDIM / 4);
    const int c = (idx % (CTEDIM / 4)) * 4;
    const float* src = (c < 1024) ? ctx + (size_t)r * 1024 + c
                     : (c < 2048) ? te  + (size_t)r * 1024 + (c - 1024)
                                  : ce  + (size_t)r * 1024 + (c - 2048);
    const float4 v = *reinterpret_cast<const float4*>(src);
    f16x4 o; o.x = (_Float16)v.x; o.y = (_Float16)v.y; o.z = (_Float16)v.z; o.w = (_Float16)v.w;
    *reinterpret_cast<f16x4*>(&out[idx * 4]) = o;
}

__global__ void build_biasSS(const float* __restrict__ bs, const float* __restrict__ bt,
                             float* __restrict__ out)
{
    const int id = blockIdx.x * 256 + threadIdx.x;   // L*256
    const int l = id >> 8, j = id & 255;
    out[id] = (j < 128) ? bs[l * 128 + j] : bt[l * 128 + (j - 128)];
}

__global__ void gather_xa0(const float* __restrict__ x, const int* __restrict__ perm,
                           const int* __restrict__ ia, _Float16* __restrict__ xa)
{
    const int r = blockIdx.x, j = threadIdx.x;   // 128 threads
    xa[(size_t)r * ADIM + j] = (_Float16)x[(size_t)r * DDIM + perm[ia[j]]];
}

// ---------------------------------------------------------------------------
__global__ void coupling_ep(const float* __restrict__ zin,
                            const float* __restrict__ ss,
                            const int* __restrict__ perm,
                            const int* __restrict__ ia_,
                            const int* __restrict__ ib_,
                            const int* __restrict__ permN,
                            const int* __restrict__ iaN,
                            float* __restrict__ zout,
                            _Float16* __restrict__ xaN,
                            const float* __restrict__ ldin,
                            float* __restrict__ ldout,
                            int first)
{
    const int r = blockIdx.x, j = threadIdx.x;   // j in [0,128)
    __shared__ float zrow[DDIM];
    __shared__ float part[2];

    const int ia = ia_[j], ib = ib_[j];
    const float xav = zin[(size_t)r * DDIM + perm[ia]];
    const float xbv = zin[(size_t)r * DDIM + perm[ib]];
    float sc = ss[(size_t)r * DDIM + j];
    sc = fminf(CLIPV, fmaxf(-CLIPV, sc));
    const float sh = ss[(size_t)r * DDIM + 128 + j];
    const float yb = xbv * __expf(sc) + sh;

    zrow[ia] = xav;
    zrow[ib] = yb;

    float v = sc;
#pragma unroll
    for (int off = 32; off; off >>= 1) v += __shfl_down(v, off, 64);
    if ((j & 63) == 0) part[j >> 6] = v;
    __syncthreads();

    zout[(size_t)r * DDIM + j]       = zrow[j];
    zout[(size_t)r * DDIM + 128 + j] = zrow[128 + j];
    if (xaN) xaN[(size_t)r * ADIM + j] = (_Float16)zrow[permN[iaN[j]]];
    if (j == 0) ldout[r] = (first ? 0.f : ldin[r]) + part[0] + part[1];
}

// ---------------------------------------------------------------------------
extern "C" void kernel_launch(void* const* d_in, const int* in_sizes, int n_in,
                              void* d_out, int out_size, void* d_ws, size_t ws_size,
                              hipStream_t stream)
{
    const float* x    = (const float*)d_in[0];
    const float* ctx  = (const float*)d_in[1];
    const float* temb = (const float*)d_in[2];
    const float* cemb = (const float*)d_in[3];
    const float* W1   = (const float*)d_in[4];
    const float* b1   = (const float*)d_in[5];
    const float* W2   = (const float*)d_in[6];
    const float* b2   = (const float*)d_in[7];
    const float* W3   = (const float*)d_in[8];
    const float* b3   = (const float*)d_in[9];
    const float* Ws   = (const float*)d_in[10];
    const float* bs   = (const float*)d_in[11];
    const float* Wt   = (const float*)d_in[12];
    const float* bt   = (const float*)d_in[13];
    const int*   perm = (const int*)d_in[14];
    const int*   idxa = (const int*)d_in[15];
    const int*   idxb = (const int*)d_in[16];

    float* out_z  = (float*)d_out;
    float* out_ld = out_z + (size_t)BROWS * DDIM;

    // ---- workspace layout (lifetime-based aliasing) ----
    _Float16* W1at = (_Float16*)d_ws;                                 // 1 M f16
    _Float16* W2t  = W1at + (size_t)L_LAYERS * HDIM * ADIM;           // 8 M
    _Float16* W3t  = W2t  + (size_t)L_LAYERS * HDIM * HDIM;           // 8 M
    _Float16* WsWtT= W3t  + (size_t)L_LAYERS * HDIM * HDIM;           // 2 M
    _Float16* xa   = WsWtT+ (size_t)L_LAYERS * 256 * HDIM;            // 1 M
    _Float16* hB   = xa   + (size_t)BROWS * ADIM;                     // 8 M
    _Float16* pre  = hB   + (size_t)BROWS * HDIM;                     // 64 M
    float* biasSS  = (float*)(pre + (size_t)BROWS * L_LAYERS * HDIM); // 2 K f32
    // cte region (24 M f16): dead after big GEMM -> hA aliases it
    _Float16* cte  = (_Float16*)(biasSS + L_LAYERS * 256);
    _Float16* hA   = cte;
    // W1ct region (24 M f16): dead after big GEMM -> fp32 temporaries alias it
    _Float16* W1ct = cte + (size_t)BROWS * CTEDIM;
    float* ssbuf   = (float*)W1ct;                                    // B*256
    float* z0      = ssbuf + (size_t)BROWS * DDIM;
    float* z1      = z0    + (size_t)BROWS * DDIM;
    float* ldacc   = z1    + (size_t)BROWS * DDIM;                    // B

    // ---- setup: weight transposes (fp32 -> f16, K x N -> N x K) ----
    transpose_to_f16<<<dim3(HDIM / 64, ADIM / 64, L_LAYERS), 256, 0, stream>>>(
        W1, W1at, ADIM, HDIM, (size_t)INDIM * HDIM, (size_t)HDIM * ADIM);
    transpose_to_f16<<<dim3(HDIM / 64, CTEDIM / 64, L_LAYERS), 256, 0, stream>>>(
        W1 + (size_t)ADIM * HDIM, W1ct, CTEDIM, HDIM,
        (size_t)INDIM * HDIM, (size_t)HDIM * CTEDIM);
    transpose_to_f16<<<dim3(HDIM / 64, HDIM / 64, L_LAYERS), 256, 0, stream>>>(
        W2, W2t, HDIM, HDIM, (size_t)HDIM * HDIM, (size_t)HDIM * HDIM);
    transpose_to_f16<<<dim3(HDIM / 64, HDIM / 64, L_LAYERS), 256, 0, stream>>>(
        W3, W3t, HDIM, HDIM, (size_t)HDIM * HDIM, (size_t)HDIM * HDIM);
    transpose_to_f16<<<dim3(BDIM_ / 64, HDIM / 64, L_LAYERS), 256, 0, stream>>>(
        Ws, WsWtT, HDIM, BDIM_, (size_t)HDIM * BDIM_, (size_t)256 * HDIM);
    transpose_to_f16<<<dim3(BDIM_ / 64, HDIM / 64, L_LAYERS), 256, 0, stream>>>(
        Wt, WsWtT + (size_t)BDIM_ * HDIM, HDIM, BDIM_, (size_t)HDIM * BDIM_, (size_t)256 * HDIM);

    build_cte<<<(BROWS * (CTEDIM / 4)) / 256, 256, 0, stream>>>(ctx, temb, cemb, cte);
    build_biasSS<<<L_LAYERS, 256, 0, stream>>>(bs, bt, biasSS);
    gather_xa0<<<BROWS, 128, 0, stream>>>(x, perm, idxa, xa);

    // ---- big layer-invariant GEMM: pre = cte @ W1c (grid 32x32, 16x8/XCD) --
    gemm8p<0, 256><<<dim3(1024), 512, 0, stream>>>(
        cte, CTEDIM, W1ct, CTEDIM, nullptr, pre, L_LAYERS * HDIM, CTEDIM,
        /*gx*/32, /*RC*/8, /*rr*/16);

    // ---- 8 coupling layers ----
    const float* zin = x;
    for (int l = 0; l < L_LAYERS; ++l) {
        const _Float16* w1a = W1at + (size_t)l * HDIM * ADIM;
        const _Float16* w2  = W2t  + (size_t)l * HDIM * HDIM;
        const _Float16* w3  = W3t  + (size_t)l * HDIM * HDIM;
        const _Float16* w4  = WsWtT+ (size_t)l * 256 * HDIM;

        // GEMM1': silu(xa @ W1a + pre[:, l*H:(l+1)*H] + b1) -> hA
        gemm_mfma<0><<<dim3(HDIM / 128, BROWS / 128), 256, 0, stream>>>(
            xa, ADIM, w1a, ADIM, b1 + (size_t)l * HDIM,
            pre + (size_t)l * HDIM, L_LAYERS * HDIM,
            hA, nullptr, HDIM, ADIM);
        // GEMM2: silu(hA @ W2 + b2) -> hB   (grid 32x8 = 256 wgs, 8x4/XCD)
        gemm8p<1, 128><<<dim3(256), 512, 0, stream>>>(
            hA, HDIM, w2, HDIM, b2 + (size_t)l * HDIM, hB, HDIM, HDIM,
            /*gx*/8, /*RC*/4, /*rr*/8);
        // GEMM3: silu(hB @ W3 + b3) -> hA
        gemm8p<1, 128><<<dim3(256), 512, 0, stream>>>(
            hB, HDIM, w3, HDIM, b3 + (size_t)l * HDIM, hA, HDIM, HDIM,
            /*gx*/8, /*RC*/4, /*rr*/8);
        // GEMM4: hA @ [Ws|Wt] + bias -> fp32 ss
        gemm_mfma<1><<<dim3(256 / 128, BROWS / 128), 256, 0, stream>>>(
            hA, HDIM, w4, HDIM, biasSS + (size_t)l * 256,
            nullptr, 0, nullptr, ssbuf, 256, HDIM);

        // epilogue
        float* zout = (l == L_LAYERS - 1) ? out_z : ((l & 1) ? z1 : z0);
        const int last = (l == L_LAYERS - 1);
        coupling_ep<<<BROWS, 128, 0, stream>>>(
            zin, ssbuf,
            perm + (size_t)l * DDIM, idxa + (size_t)l * ADIM, idxb + (size_t)l * ADIM,
            last ? nullptr : perm + (size_t)(l + 1) * DDIM,
            last ? nullptr : idxa + (size_t)(l + 1) * ADIM,
            zout, last ? nullptr : xa,
            ldacc, last ? out_ld : ldacc, l == 0);
        zin = zout;
    }
}